// Round 13
// baseline (231.530 us; speedup 1.0000x reference)
//
#include <hip/hip_runtime.h>
#include <hip/hip_fp16.h>
#include <math.h>

#define NEG_SLOPE 0.2f
#define EPS_SM 1e-8f
#define EPS_LN 1e-5f
#define PAD 16          // one global counter per 64B line
#define BSH 8           // bucket = dst >> 8  (256 nodes/bucket)
#define NBMAX 512       // max buckets (n <= 131072)
#define CHUNK 2048      // edges per pass1/bhist block
#define SEGCAP 2816     // idx16 capacity per half-bucket (mean 2048 + 17 sigma)

// round-to-nearest bf16 pair pack: returns (bf16(b)<<16) | bf16(a)
__device__ inline unsigned bf16pair(float a, float b)
{
    unsigned ua = __float_as_uint(a), ub = __float_as_uint(b);
    ua = (ua + 0x7fffu + ((ua >> 16) & 1u)) >> 16;
    ub = (ub + 0x7fffu + ((ub >> 16) & 1u)) >> 16;
    return ua | (ub << 16);
}

// ---------------------------------------------------------------------------
// Kernel 1: h = x @ W_node (64x64) + fused a_src/a_dst projections.
// 64 rows per 256-thread block, register-tiled 4x4 per thread. h stored f16.
// ---------------------------------------------------------------------------
__global__ __launch_bounds__(256) void k_node(
    const float* __restrict__ x, const float* __restrict__ Wn,
    const float* __restrict__ attn_src, const float* __restrict__ attn_dst,
    __half* __restrict__ h16, float* __restrict__ a_src, float* __restrict__ a_dst,
    int n)
{
    __shared__ float Ws[64][64];   // W[k][col]
    __shared__ float xs[64][64];   // x[r][k]
    const int tid  = threadIdx.x;
    const int row0 = blockIdx.x * 64;

    const float4* Wn4 = (const float4*)Wn;
    #pragma unroll
    for (int i = tid; i < 1024; i += 256) {
        float4 v = Wn4[i];
        *(float4*)&Ws[i >> 4][(i & 15) * 4] = v;
    }
    const float4* x4 = (const float4*)x;
    #pragma unroll
    for (int i = tid; i < 1024; i += 256) {
        int r  = i >> 4;
        int gr = row0 + r;
        float4 v = (gr < n) ? x4[(size_t)gr * 16 + (i & 15)]
                            : make_float4(0.f, 0.f, 0.f, 0.f);
        *(float4*)&xs[r][(i & 15) * 4] = v;
    }
    __syncthreads();

    const int c4 = tid & 15;
    const int r4 = tid >> 4;

    float4 acc0 = make_float4(0.f, 0.f, 0.f, 0.f);
    float4 acc1 = make_float4(0.f, 0.f, 0.f, 0.f);
    float4 acc2 = make_float4(0.f, 0.f, 0.f, 0.f);
    float4 acc3 = make_float4(0.f, 0.f, 0.f, 0.f);

    #pragma unroll 8
    for (int k = 0; k < 64; ++k) {
        float4 w = *(const float4*)&Ws[k][c4 * 4];
        float x0 = xs[r4     ][k];
        float x1 = xs[r4 + 16][k];
        float x2 = xs[r4 + 32][k];
        float x3 = xs[r4 + 48][k];
        acc0.x += x0 * w.x; acc0.y += x0 * w.y; acc0.z += x0 * w.z; acc0.w += x0 * w.w;
        acc1.x += x1 * w.x; acc1.y += x1 * w.y; acc1.z += x1 * w.z; acc1.w += x1 * w.w;
        acc2.x += x2 * w.x; acc2.y += x2 * w.y; acc2.z += x2 * w.z; acc2.w += x2 * w.w;
        acc3.x += x3 * w.x; acc3.y += x3 * w.y; acc3.z += x3 * w.z; acc3.w += x3 * w.w;
    }

    const float4 asw = *(const float4*)&attn_src[c4 * 4];
    const float4 adw = *(const float4*)&attn_dst[c4 * 4];
    const int hh = c4 >> 2;
    const bool writer = (c4 & 3) == 0;

    float4 accs[4] = {acc0, acc1, acc2, acc3};
    #pragma unroll
    for (int j = 0; j < 4; ++j) {
        int gr = row0 + r4 + 16 * j;
        if (gr < n) {
            __half2 p0 = __floats2half2_rn(accs[j].x, accs[j].y);
            __half2 p1 = __floats2half2_rn(accs[j].z, accs[j].w);
            uint2 pk = make_uint2(*reinterpret_cast<unsigned*>(&p0),
                                  *reinterpret_cast<unsigned*>(&p1));
            *(uint2*)&h16[(size_t)gr * 64 + c4 * 4] = pk;
            float ps = accs[j].x * asw.x + accs[j].y * asw.y +
                       accs[j].z * asw.z + accs[j].w * asw.w;
            float pd = accs[j].x * adw.x + accs[j].y * adw.y +
                       accs[j].z * adw.z + accs[j].w * adw.w;
            ps += __shfl_xor(ps, 1, 64); ps += __shfl_xor(ps, 2, 64);
            pd += __shfl_xor(pd, 1, 64); pd += __shfl_xor(pd, 2, 64);
            if (writer) {
                a_src[(size_t)gr * 4 + hh] = ps;
                a_dst[(size_t)gr * 4 + hh] = pd;
            }
        } else {
            float ps = 0.f, pd = 0.f;
            ps += __shfl_xor(ps, 1, 64); ps += __shfl_xor(ps, 2, 64);
            pd += __shfl_xor(pd, 1, 64); pd += __shfl_xor(pd, 2, 64);
        }
    }
}

// ---------------------------------------------------------------------------
// Kernel 2: bucket histogram (LDS-staged, one global add per (chunk,bucket)).
// ---------------------------------------------------------------------------
__global__ __launch_bounds__(256) void k_bhist(
    const int* __restrict__ dst, int* __restrict__ gbcnt, int E)
{
    __shared__ int cnt[NBMAX];
    const int tid = threadIdx.x;
    for (int i = tid; i < NBMAX; i += 256) cnt[i] = 0;
    __syncthreads();
    const int e0 = blockIdx.x * CHUNK;
    const int ce = min(CHUNK, E - e0);
    for (int j = tid; j < ce; j += 256)
        atomicAdd(&cnt[((unsigned)dst[e0 + j]) >> BSH], 1);
    __syncthreads();
    for (int b = tid; b < NBMAX; b += 256)
        if (cnt[b] > 0) atomicAdd(&gbcnt[b * PAD], cnt[b]);
}

// ---------------------------------------------------------------------------
// Kernel 3: exclusive scan of 512 bucket counts (one wave).
// ---------------------------------------------------------------------------
__global__ void k_bscan(const int* __restrict__ gbcnt,
                        int* __restrict__ bstart, int* __restrict__ bcount,
                        int* __restrict__ bcur)
{
    int lane = threadIdx.x;   // 64 threads
    int c[8]; int s = 0;
    #pragma unroll
    for (int j = 0; j < 8; ++j) { c[j] = gbcnt[(lane * 8 + j) * PAD]; s += c[j]; }
    int incl = s;
    #pragma unroll
    for (int off = 1; off < 64; off <<= 1) {
        int u = __shfl_up(incl, off, 64);
        if (lane >= off) incl += u;
    }
    int run = incl - s;
    #pragma unroll
    for (int j = 0; j < 8; ++j) {
        int b = lane * 8 + j;
        bstart[b] = run;
        bcount[b] = c[j];
        bcur[b * PAD] = run;
        run += c[j];
    }
}

// ---------------------------------------------------------------------------
// Kernel 4: bucket-grouped scatter + FULL weight computation.
// 512 threads, 4 edges/thread. Gathers a_src[src] AND a_dst[dst] (both
// L2/L3-resident), computes w = exp(lrelu(a_src+esc+a_dst)) in f32, packs
// bf16x4. Record: int4 { src, bf16x2(w0,w1), bf16x2(w2,w3), dst }.
// One global atomic per non-empty bucket reserves a contiguous run.
// ---------------------------------------------------------------------------
__global__ __launch_bounds__(512) void k_pass1(
    const int* __restrict__ src, const int* __restrict__ dst,
    const float* __restrict__ ea, const float* __restrict__ We,
    const float* __restrict__ a_src, const float* __restrict__ a_dst,
    int* __restrict__ bcur, int4* __restrict__ rec_out,
    unsigned char* __restrict__ dl8_out, int E)
{
    __shared__ float Wes[64];       // W_edge [16][4]
    __shared__ int cnt[NBMAX];      // 2KB
    __shared__ int gpos[NBMAX];     // 2KB
    const int tid = threadIdx.x;
    if (tid < 64) Wes[tid] = We[tid];
    for (int i = tid; i < NBMAX; i += 512) cnt[i] = 0;
    __syncthreads();

    const int e0 = blockIdx.x * CHUNK;
    int d[4], s[4], rk[4];
    #pragma unroll
    for (int j = 0; j < 4; ++j) {
        int e = e0 + j * 512 + tid;
        bool v = e < E;
        d[j] = v ? dst[e] : -1;
        s[j] = v ? src[e] : 0;
    }

    #pragma unroll
    for (int j = 0; j < 4; ++j)
        rk[j] = (d[j] >= 0) ? atomicAdd(&cnt[((unsigned)d[j]) >> BSH], 1) : 0;

    // both attention-side gathers issued up-front (independent, L2/L3-hot)
    float4 as4[4], ad4[4];
    #pragma unroll
    for (int j = 0; j < 4; ++j) {
        as4[j] = (d[j] >= 0) ? *(const float4*)(a_src + (size_t)s[j] * 4)
                             : make_float4(0.f, 0.f, 0.f, 0.f);
        ad4[j] = (d[j] >= 0) ? *(const float4*)(a_dst + (size_t)d[j] * 4)
                             : make_float4(0.f, 0.f, 0.f, 0.f);
    }

    int ry[4], rz[4];
    #pragma unroll
    for (int j = 0; j < 4; ++j) {
        if (d[j] < 0) { ry[j] = 0; rz[j] = 0; continue; }
        int e = e0 + j * 512 + tid;
        const float4* ea4 = (const float4*)(ea + (size_t)e * 16);
        float4 q0 = ea4[0], q1 = ea4[1], q2 = ea4[2], q3 = ea4[3];
        float eav[16] = {q0.x, q0.y, q0.z, q0.w, q1.x, q1.y, q1.z, q1.w,
                         q2.x, q2.y, q2.z, q2.w, q3.x, q3.y, q3.z, q3.w};
        float esc[4] = {0.f, 0.f, 0.f, 0.f};
        #pragma unroll
        for (int k = 0; k < 16; ++k) {
            #pragma unroll
            for (int hh = 0; hh < 4; ++hh) esc[hh] += eav[k] * Wes[k * 4 + hh];
        }
        float a0 = as4[j].x + esc[0] + ad4[j].x;
        float a1 = as4[j].y + esc[1] + ad4[j].y;
        float a2 = as4[j].z + esc[2] + ad4[j].z;
        float a3 = as4[j].w + esc[3] + ad4[j].w;
        a0 = (a0 >= 0.f) ? a0 : NEG_SLOPE * a0;
        a1 = (a1 >= 0.f) ? a1 : NEG_SLOPE * a1;
        a2 = (a2 >= 0.f) ? a2 : NEG_SLOPE * a2;
        a3 = (a3 >= 0.f) ? a3 : NEG_SLOPE * a3;
        ry[j] = (int)bf16pair(__expf(a0), __expf(a1));
        rz[j] = (int)bf16pair(__expf(a2), __expf(a3));
    }
    __syncthreads();

    for (int b = tid; b < NBMAX; b += 512)
        if (cnt[b] > 0) gpos[b] = atomicAdd(&bcur[b * PAD], cnt[b]);
    __syncthreads();

    #pragma unroll
    for (int j = 0; j < 4; ++j) {
        if (d[j] < 0) continue;
        int g = gpos[((unsigned)d[j]) >> BSH] + rk[j];
        rec_out[g] = make_int4(s[j], ry[j], rz[j], d[j]);
        dl8_out[g] = (unsigned char)(d[j] & 255);
    }
}

// ---------------------------------------------------------------------------
// Kernel 5 (fused bin + aggregate + LayerNorm): 2 sub-blocks per bucket,
// 512 threads each. Phase A: bin the half-bucket's edge ids into LDS idx16
// (two passes over the 4KB dl8 stream + 128-counter scan). Phase B: wave-
// per-node; records fetched via wave-uniform 16B loads from the L2-hot
// bucket region (weights precomputed in pass1 — no shuffles, no exp).
// ---------------------------------------------------------------------------
__global__ __launch_bounds__(512) void k_fuse(
    const int* __restrict__ bstart, const int* __restrict__ bcount,
    const int4* __restrict__ recs, const unsigned char* __restrict__ dl8,
    const __half* __restrict__ h16,
    const float* __restrict__ gamma, const float* __restrict__ beta,
    float* __restrict__ out, int n)
{
    __shared__ unsigned short idx16[SEGCAP];   // 5.5KB
    __shared__ int cnt[128], st[128], cur[128];
    const int b    = blockIdx.x >> 1;
    const int sub  = blockIdx.x & 1;
    const int tid  = threadIdx.x;
    const int dlo  = sub * 128;
    const int nbase = (b << BSH) + dlo;
    if (nbase >= n) return;

    const int base = bstart[b];
    const int bcnt = bcount[b];

    if (tid < 128) cnt[tid] = 0;
    __syncthreads();
    for (int i = tid; i < bcnt; i += 512) {
        int dl = (int)dl8[base + i] - dlo;
        if ((unsigned)dl < 128u) atomicAdd(&cnt[dl], 1);
    }
    __syncthreads();
    if (tid < 64) {
        int c0 = cnt[2 * tid], c1 = cnt[2 * tid + 1];
        int s = c0 + c1;
        int incl = s;
        #pragma unroll
        for (int off = 1; off < 64; off <<= 1) {
            int u = __shfl_up(incl, off, 64);
            if (tid >= off) incl += u;
        }
        int run = incl - s;
        st[2 * tid    ] = run;      cur[2 * tid    ] = run;
        st[2 * tid + 1] = run + c0; cur[2 * tid + 1] = run + c0;
    }
    __syncthreads();
    for (int i = tid; i < bcnt; i += 512) {
        int dl = (int)dl8[base + i] - dlo;
        if ((unsigned)dl < 128u) {
            int p = atomicAdd(&cur[dl], 1);
            if (p < SEGCAP) idx16[p] = (unsigned short)i;
        }
    }
    __syncthreads();

    const int lane = tid & 63;
    const int wv   = tid >> 6;            // 0..7
    const int hh   = lane >> 4;
    const int wsh  = (hh & 1) ? 0 : 16;   // bf16 lane-slot shift

#define PROC_EDGE(HV, YW, ZW)                                            \
    {                                                                    \
        int w_ = (hh < 2) ? (YW) : (ZW);                                 \
        float wf_ = __int_as_float(((unsigned)w_ << wsh) & 0xffff0000u); \
        sum  += wf_;                                                     \
        accv += wf_ * (HV);                                              \
    }

    #pragma unroll 1
    for (int k = 0; k < 16; ++k) {
        int dl = wv * 16 + k;
        int node = nbase + dl;
        if (node >= n) continue;
        int rsl = st[dl];
        int deg = cnt[dl];
        // overflow clamp (statistically unreachable: SEGCAP = mean + 17 sigma)
        int end = min(rsl + deg, SEGCAP);
        deg = (end > rsl) ? (end - rsl) : 0;

        float h_node = __half2float(h16[((unsigned)node << 6) | lane]);
        float sum = 0.f, accv = 0.f;

        int i = 0;
        for (; i + 4 <= deg; i += 4) {
            int id0 = idx16[rsl + i + 0];
            int id1 = idx16[rsl + i + 1];
            int id2 = idx16[rsl + i + 2];
            int id3 = idx16[rsl + i + 3];
            int4 r0 = recs[(size_t)base + id0];
            int4 r1 = recs[(size_t)base + id1];
            int4 r2 = recs[(size_t)base + id2];
            int4 r3 = recs[(size_t)base + id3];
            float hv0 = __half2float(h16[((unsigned)r0.x << 6) | lane]);
            float hv1 = __half2float(h16[((unsigned)r1.x << 6) | lane]);
            float hv2 = __half2float(h16[((unsigned)r2.x << 6) | lane]);
            float hv3 = __half2float(h16[((unsigned)r3.x << 6) | lane]);
            PROC_EDGE(hv0, r0.y, r0.z);
            PROC_EDGE(hv1, r1.y, r1.z);
            PROC_EDGE(hv2, r2.y, r2.z);
            PROC_EDGE(hv3, r3.y, r3.z);
        }
        for (; i < deg; ++i) {
            int id0 = idx16[rsl + i];
            int4 r0 = recs[(size_t)base + id0];
            float hv0 = __half2float(h16[((unsigned)r0.x << 6) | lane]);
            PROC_EDGE(hv0, r0.y, r0.z);
        }

        float y = accv / (sum + EPS_SM) + h_node;

        float t1 = y;
        #pragma unroll
        for (int off = 32; off; off >>= 1) t1 += __shfl_xor(t1, off, 64);
        float mu = t1 * (1.f / 64.f);
        float dv = y - mu;
        float vs = dv * dv;
        #pragma unroll
        for (int off = 32; off; off >>= 1) vs += __shfl_xor(vs, off, 64);
        float var = vs * (1.f / 64.f);
        out[((unsigned)node << 6) | lane] =
            dv * rsqrtf(var + EPS_LN) * gamma[lane] + beta[lane];
    }
#undef PROC_EDGE
}

// ---------------------------------------------------------------------------
extern "C" void kernel_launch(void* const* d_in, const int* in_sizes, int n_in,
                              void* d_out, int out_size, void* d_ws, size_t ws_size,
                              hipStream_t stream)
{
    const float* x     = (const float*)d_in[0];
    const int*   ei    = (const int*)  d_in[1];
    const float* ea    = (const float*)d_in[2];
    const float* Wn    = (const float*)d_in[3];
    const float* We    = (const float*)d_in[4];
    const float* asrcW = (const float*)d_in[5];
    const float* adstW = (const float*)d_in[6];
    const float* gamma = (const float*)d_in[7];
    const float* beta  = (const float*)d_in[8];
    float* out = (float*)d_out;

    const int n = in_sizes[0] / 64;
    const int E = in_sizes[1] / 2;
    const int* src = ei;
    const int* dst = ei + E;
    const int NB = (n + 255) >> BSH;
    const int nchunk = (E + CHUNK - 1) / CHUNK;

    float* ws = (float*)d_ws;
    size_t off = 0;
    __half* h16  = (__half*)(ws + off); off += (size_t)n * 32;   // n*64 halves
    float* a_src = ws + off; off += (size_t)n * 4;
    float* a_dst = ws + off; off += (size_t)n * 4;
    int4* recs   = (int4*)(ws + off); off += (size_t)E * 4;
    unsigned char* dl8 = (unsigned char*)(ws + off); off += ((size_t)E + 3) / 4;
    int* ibase  = (int*)(ws + off);
    int* gbcnt  = ibase;                       // NBMAX*PAD
    int* bcur   = ibase + NBMAX * PAD;         // NBMAX*PAD
    int* bstart = ibase + 2 * NBMAX * PAD;     // NBMAX
    int* bcount = bstart + NBMAX;              // NBMAX

    hipMemsetAsync(gbcnt, 0, (size_t)NBMAX * PAD * sizeof(int), stream);

    k_node<<<(n + 63) / 64, 256, 0, stream>>>(x, Wn, asrcW, adstW, h16, a_src, a_dst, n);
    k_bhist<<<nchunk, 256, 0, stream>>>(dst, gbcnt, E);
    k_bscan<<<1, 64, 0, stream>>>(gbcnt, bstart, bcount, bcur);
    k_pass1<<<nchunk, 512, 0, stream>>>(src, dst, ea, We, a_src, a_dst,
                                        bcur, recs, dl8, E);
    k_fuse<<<NB * 2, 512, 0, stream>>>(bstart, bcount, recs, dl8, h16,
                                       gamma, beta, out, n);
}

// Round 14
// 193.961 us; speedup vs baseline: 1.1937x; 1.1937x over previous
//
#include <hip/hip_runtime.h>
#include <hip/hip_fp16.h>
#include <math.h>

#define NEG_SLOPE 0.2f
#define EPS_SM 1e-8f
#define EPS_LN 1e-5f
#define PAD 16          // one global counter per 64B line
#define BSH 8           // bucket = dst >> 8  (256 nodes/bucket)
#define NBMAX 512       // max buckets (n <= 131072)
#define CHUNK 2048      // edges per pass1/bhist block

// round-to-nearest bf16 pair pack: returns (bf16(b)<<16) | bf16(a)
__device__ inline unsigned bf16pair(float a, float b)
{
    unsigned ua = __float_as_uint(a), ub = __float_as_uint(b);
    ua = (ua + 0x7fffu + ((ua >> 16) & 1u)) >> 16;
    ub = (ub + 0x7fffu + ((ub >> 16) & 1u)) >> 16;
    return ua | (ub << 16);
}

// ---------------------------------------------------------------------------
// Kernel 1 (fused): blocks [0, nbNode) do h = x @ W_node + a_src/a_dst
// projections (64 rows/block, register-tiled 4x4, h stored f16).
// Blocks [nbNode, nbNode+nchunk) do the bucket histogram over dst
// (LDS-staged in Ws' storage, one global add per (chunk,bucket)).
// ---------------------------------------------------------------------------
__global__ __launch_bounds__(256) void k_node_hist(
    const float* __restrict__ x, const float* __restrict__ Wn,
    const float* __restrict__ attn_src, const float* __restrict__ attn_dst,
    __half* __restrict__ h16, float* __restrict__ a_src, float* __restrict__ a_dst,
    int n, const int* __restrict__ dst, int* __restrict__ gbcnt, int E, int nbNode)
{
    __shared__ float Ws[64][64];   // W[k][col]   (bhist: reused as cnt[])
    __shared__ float xs[64][64];   // x[r][k]
    const int tid = threadIdx.x;

    if (blockIdx.x >= nbNode) {
        // ---- bucket histogram branch ----
        int* cnt = (int*)Ws;
        for (int i = tid; i < NBMAX; i += 256) cnt[i] = 0;
        __syncthreads();
        const int e0 = (blockIdx.x - nbNode) * CHUNK;
        const int ce = min(CHUNK, E - e0);
        for (int j = tid; j < ce; j += 256)
            atomicAdd(&cnt[((unsigned)dst[e0 + j]) >> BSH], 1);
        __syncthreads();
        for (int b = tid; b < NBMAX; b += 256)
            if (cnt[b] > 0) atomicAdd(&gbcnt[b * PAD], cnt[b]);
        return;
    }

    // ---- node GEMM branch ----
    const int row0 = blockIdx.x * 64;

    const float4* Wn4 = (const float4*)Wn;
    #pragma unroll
    for (int i = tid; i < 1024; i += 256) {
        float4 v = Wn4[i];
        *(float4*)&Ws[i >> 4][(i & 15) * 4] = v;
    }
    const float4* x4 = (const float4*)x;
    #pragma unroll
    for (int i = tid; i < 1024; i += 256) {
        int r  = i >> 4;
        int gr = row0 + r;
        float4 v = (gr < n) ? x4[(size_t)gr * 16 + (i & 15)]
                            : make_float4(0.f, 0.f, 0.f, 0.f);
        *(float4*)&xs[r][(i & 15) * 4] = v;
    }
    __syncthreads();

    const int c4 = tid & 15;
    const int r4 = tid >> 4;

    float4 acc0 = make_float4(0.f, 0.f, 0.f, 0.f);
    float4 acc1 = make_float4(0.f, 0.f, 0.f, 0.f);
    float4 acc2 = make_float4(0.f, 0.f, 0.f, 0.f);
    float4 acc3 = make_float4(0.f, 0.f, 0.f, 0.f);

    #pragma unroll 8
    for (int k = 0; k < 64; ++k) {
        float4 w = *(const float4*)&Ws[k][c4 * 4];
        float x0 = xs[r4     ][k];
        float x1 = xs[r4 + 16][k];
        float x2 = xs[r4 + 32][k];
        float x3 = xs[r4 + 48][k];
        acc0.x += x0 * w.x; acc0.y += x0 * w.y; acc0.z += x0 * w.z; acc0.w += x0 * w.w;
        acc1.x += x1 * w.x; acc1.y += x1 * w.y; acc1.z += x1 * w.z; acc1.w += x1 * w.w;
        acc2.x += x2 * w.x; acc2.y += x2 * w.y; acc2.z += x2 * w.z; acc2.w += x2 * w.w;
        acc3.x += x3 * w.x; acc3.y += x3 * w.y; acc3.z += x3 * w.z; acc3.w += x3 * w.w;
    }

    const float4 asw = *(const float4*)&attn_src[c4 * 4];
    const float4 adw = *(const float4*)&attn_dst[c4 * 4];
    const int hh = c4 >> 2;
    const bool writer = (c4 & 3) == 0;

    float4 accs[4] = {acc0, acc1, acc2, acc3};
    #pragma unroll
    for (int j = 0; j < 4; ++j) {
        int gr = row0 + r4 + 16 * j;
        if (gr < n) {
            __half2 p0 = __floats2half2_rn(accs[j].x, accs[j].y);
            __half2 p1 = __floats2half2_rn(accs[j].z, accs[j].w);
            uint2 pk = make_uint2(*reinterpret_cast<unsigned*>(&p0),
                                  *reinterpret_cast<unsigned*>(&p1));
            *(uint2*)&h16[(size_t)gr * 64 + c4 * 4] = pk;
            float ps = accs[j].x * asw.x + accs[j].y * asw.y +
                       accs[j].z * asw.z + accs[j].w * asw.w;
            float pd = accs[j].x * adw.x + accs[j].y * adw.y +
                       accs[j].z * adw.z + accs[j].w * adw.w;
            ps += __shfl_xor(ps, 1, 64); ps += __shfl_xor(ps, 2, 64);
            pd += __shfl_xor(pd, 1, 64); pd += __shfl_xor(pd, 2, 64);
            if (writer) {
                a_src[(size_t)gr * 4 + hh] = ps;
                a_dst[(size_t)gr * 4 + hh] = pd;
            }
        } else {
            float ps = 0.f, pd = 0.f;
            ps += __shfl_xor(ps, 1, 64); ps += __shfl_xor(ps, 2, 64);
            pd += __shfl_xor(pd, 1, 64); pd += __shfl_xor(pd, 2, 64);
        }
    }
}

// ---------------------------------------------------------------------------
// Kernel 2: exclusive scan of 512 bucket counts (one wave).
// ---------------------------------------------------------------------------
__global__ void k_bscan(const int* __restrict__ gbcnt,
                        int* __restrict__ bstart, int* __restrict__ bcount,
                        int* __restrict__ bcur)
{
    int lane = threadIdx.x;   // 64 threads
    int c[8]; int s = 0;
    #pragma unroll
    for (int j = 0; j < 8; ++j) { c[j] = gbcnt[(lane * 8 + j) * PAD]; s += c[j]; }
    int incl = s;
    #pragma unroll
    for (int off = 1; off < 64; off <<= 1) {
        int u = __shfl_up(incl, off, 64);
        if (lane >= off) incl += u;
    }
    int run = incl - s;
    #pragma unroll
    for (int j = 0; j < 8; ++j) {
        int b = lane * 8 + j;
        bstart[b] = run;
        bcount[b] = c[j];
        bcur[b * PAD] = run;
        run += c[j];
    }
}

// ---------------------------------------------------------------------------
// Kernel 3: bucket-grouped scatter + FULL weight computation (f32 logits).
// 512 threads, 4 edges/thread. Gathers a_src[src] AND a_dst[dst] (both
// L2/L3-resident), computes w = exp(lrelu(a_src+esc+a_dst)), packs bf16x4.
// Record: int4 { src, bf16x2(w0,w1), bf16x2(w2,w3), dst }.
// ---------------------------------------------------------------------------
__global__ __launch_bounds__(512) void k_pass1(
    const int* __restrict__ src, const int* __restrict__ dst,
    const float* __restrict__ ea, const float* __restrict__ We,
    const float* __restrict__ a_src, const float* __restrict__ a_dst,
    int* __restrict__ bcur, int4* __restrict__ rec_out,
    unsigned char* __restrict__ dl8_out, int E)
{
    __shared__ float Wes[64];       // W_edge [16][4]
    __shared__ int cnt[NBMAX];      // 2KB
    __shared__ int gpos[NBMAX];     // 2KB
    const int tid = threadIdx.x;
    if (tid < 64) Wes[tid] = We[tid];
    for (int i = tid; i < NBMAX; i += 512) cnt[i] = 0;
    __syncthreads();

    const int e0 = blockIdx.x * CHUNK;
    int d[4], s[4], rk[4];
    #pragma unroll
    for (int j = 0; j < 4; ++j) {
        int e = e0 + j * 512 + tid;
        bool v = e < E;
        d[j] = v ? dst[e] : -1;
        s[j] = v ? src[e] : 0;
    }

    #pragma unroll
    for (int j = 0; j < 4; ++j)
        rk[j] = (d[j] >= 0) ? atomicAdd(&cnt[((unsigned)d[j]) >> BSH], 1) : 0;

    float4 as4[4], ad4[4];
    #pragma unroll
    for (int j = 0; j < 4; ++j) {
        as4[j] = (d[j] >= 0) ? *(const float4*)(a_src + (size_t)s[j] * 4)
                             : make_float4(0.f, 0.f, 0.f, 0.f);
        ad4[j] = (d[j] >= 0) ? *(const float4*)(a_dst + (size_t)d[j] * 4)
                             : make_float4(0.f, 0.f, 0.f, 0.f);
    }

    int ry[4], rz[4];
    #pragma unroll
    for (int j = 0; j < 4; ++j) {
        if (d[j] < 0) { ry[j] = 0; rz[j] = 0; continue; }
        int e = e0 + j * 512 + tid;
        const float4* ea4 = (const float4*)(ea + (size_t)e * 16);
        float4 q0 = ea4[0], q1 = ea4[1], q2 = ea4[2], q3 = ea4[3];
        float eav[16] = {q0.x, q0.y, q0.z, q0.w, q1.x, q1.y, q1.z, q1.w,
                         q2.x, q2.y, q2.z, q2.w, q3.x, q3.y, q3.z, q3.w};
        float esc[4] = {0.f, 0.f, 0.f, 0.f};
        #pragma unroll
        for (int k = 0; k < 16; ++k) {
            #pragma unroll
            for (int hh = 0; hh < 4; ++hh) esc[hh] += eav[k] * Wes[k * 4 + hh];
        }
        float a0 = as4[j].x + esc[0] + ad4[j].x;
        float a1 = as4[j].y + esc[1] + ad4[j].y;
        float a2 = as4[j].z + esc[2] + ad4[j].z;
        float a3 = as4[j].w + esc[3] + ad4[j].w;
        a0 = (a0 >= 0.f) ? a0 : NEG_SLOPE * a0;
        a1 = (a1 >= 0.f) ? a1 : NEG_SLOPE * a1;
        a2 = (a2 >= 0.f) ? a2 : NEG_SLOPE * a2;
        a3 = (a3 >= 0.f) ? a3 : NEG_SLOPE * a3;
        ry[j] = (int)bf16pair(__expf(a0), __expf(a1));
        rz[j] = (int)bf16pair(__expf(a2), __expf(a3));
    }
    __syncthreads();

    for (int b = tid; b < NBMAX; b += 512)
        if (cnt[b] > 0) gpos[b] = atomicAdd(&bcur[b * PAD], cnt[b]);
    __syncthreads();

    #pragma unroll
    for (int j = 0; j < 4; ++j) {
        if (d[j] < 0) continue;
        int g = gpos[((unsigned)d[j]) >> BSH] + rk[j];
        rec_out[g] = make_int4(s[j], ry[j], rz[j], d[j]);
        dl8_out[g] = (unsigned char)(d[j] & 255);
    }
}

// ---------------------------------------------------------------------------
// Kernel 4: per-bucket counting sort to per-node-contiguous order (pure
// permutation — weights already in the record). Emits recs2 + nstart/ndeg.
// All record traffic L2/L3-hot (just written by pass1).
// ---------------------------------------------------------------------------
__global__ __launch_bounds__(1024) void k_bin(
    const int* __restrict__ bstart, const int* __restrict__ bcount,
    const int4* __restrict__ recs, const unsigned char* __restrict__ dl8,
    int4* __restrict__ recs2, int* __restrict__ nstart, int* __restrict__ ndeg,
    int n)
{
    __shared__ int cnt[256], st[256], cur[256];
    const int b    = blockIdx.x;
    const int tid  = threadIdx.x;
    const int nbase = b << BSH;
    const int base = bstart[b];
    const int bcnt = bcount[b];

    if (tid < 256) cnt[tid] = 0;
    __syncthreads();

    for (int i = tid; i < bcnt; i += 1024)
        atomicAdd(&cnt[dl8[base + i]], 1);
    __syncthreads();

    if (tid < 64) {
        int c0 = cnt[4 * tid], c1 = cnt[4 * tid + 1];
        int c2 = cnt[4 * tid + 2], c3 = cnt[4 * tid + 3];
        int s = c0 + c1 + c2 + c3;
        int incl = s;
        #pragma unroll
        for (int off = 1; off < 64; off <<= 1) {
            int u = __shfl_up(incl, off, 64);
            if (tid >= off) incl += u;
        }
        int run = incl - s;
        st[4 * tid    ] = run; cur[4 * tid    ] = run; run += c0;
        st[4 * tid + 1] = run; cur[4 * tid + 1] = run; run += c1;
        st[4 * tid + 2] = run; cur[4 * tid + 2] = run; run += c2;
        st[4 * tid + 3] = run; cur[4 * tid + 3] = run;
    }
    __syncthreads();

    if (tid < 256) {
        int node = nbase + tid;
        if (node < n) {
            nstart[node] = base + st[tid];
            ndeg[node]   = cnt[tid];
        }
    }

    for (int i = tid; i < bcnt; i += 1024) {
        int4 r = recs[base + i];
        int p = atomicAdd(&cur[r.w & 255], 1);
        recs2[base + p] = r;
    }
}

// ---------------------------------------------------------------------------
// Kernel 5: wave-per-node aggregation + residual + LayerNorm.
// Records are node-contiguous AND wave-uniform: readfirstlane makes the
// record address scalar so fetches go through the scalar cache
// (s_load_dwordx4), freeing the VMEM pipe for h-gathers and removing all
// shfl/DS traffic. Per edge: select + 2 bit-ops + fma + add + h16 cvt.
// ---------------------------------------------------------------------------
__global__ __launch_bounds__(256) void k_agg(
    const int* __restrict__ nstart, const int* __restrict__ ndeg,
    const int4* __restrict__ recs2, const __half* __restrict__ h16,
    const float* __restrict__ gamma, const float* __restrict__ beta,
    float* __restrict__ out, int n)
{
    int gid  = blockIdx.x * 256 + threadIdx.x;
    int node = gid >> 6;
    int lane = gid & 63;
    if (node >= n) return;
    const int hh   = lane >> 4;
    const int wsh  = (hh & 1) ? 0 : 16;   // bf16 lane-slot shift

    const unsigned rs = (unsigned)__builtin_amdgcn_readfirstlane(nstart[node]);
    const int deg     = __builtin_amdgcn_readfirstlane(ndeg[node]);
    const int4* pr = recs2 + rs;

    const float h_node = __half2float(h16[((unsigned)node << 6) | lane]);

    float sum = 0.f, accv = 0.f;

#define PROC_EDGE(HV, YW, ZW)                                            \
    {                                                                    \
        int w_ = (hh < 2) ? (YW) : (ZW);                                 \
        float wf_ = __int_as_float(((unsigned)w_ << wsh) & 0xffff0000u); \
        sum  += wf_;                                                     \
        accv += wf_ * (HV);                                              \
    }

    int i = 0;
    for (; i + 8 <= deg; i += 8) {
        int4 r[8];
        #pragma unroll
        for (int j = 0; j < 8; ++j) r[j] = pr[i + j];   // wave-uniform (SMEM)
        float hv[8];
        #pragma unroll
        for (int j = 0; j < 8; ++j)
            hv[j] = __half2float(h16[((unsigned)r[j].x << 6) | lane]);
        #pragma unroll
        for (int j = 0; j < 8; ++j) PROC_EDGE(hv[j], r[j].y, r[j].z);
    }
    for (; i < deg; ++i) {
        int4 r0 = pr[i];
        float hv0 = __half2float(h16[((unsigned)r0.x << 6) | lane]);
        PROC_EDGE(hv0, r0.y, r0.z);
    }
#undef PROC_EDGE

    float y = accv / (sum + EPS_SM) + h_node;

    float t1 = y;
    #pragma unroll
    for (int off = 32; off; off >>= 1) t1 += __shfl_xor(t1, off, 64);
    float mu = t1 * (1.f / 64.f);
    float dv = y - mu;
    float vs = dv * dv;
    #pragma unroll
    for (int off = 32; off; off >>= 1) vs += __shfl_xor(vs, off, 64);
    float var = vs * (1.f / 64.f);
    out[((unsigned)node << 6) | lane] =
        dv * rsqrtf(var + EPS_LN) * gamma[lane] + beta[lane];
}

// ---------------------------------------------------------------------------
extern "C" void kernel_launch(void* const* d_in, const int* in_sizes, int n_in,
                              void* d_out, int out_size, void* d_ws, size_t ws_size,
                              hipStream_t stream)
{
    const float* x     = (const float*)d_in[0];
    const int*   ei    = (const int*)  d_in[1];
    const float* ea    = (const float*)d_in[2];
    const float* Wn    = (const float*)d_in[3];
    const float* We    = (const float*)d_in[4];
    const float* asrcW = (const float*)d_in[5];
    const float* adstW = (const float*)d_in[6];
    const float* gamma = (const float*)d_in[7];
    const float* beta  = (const float*)d_in[8];
    float* out = (float*)d_out;

    const int n = in_sizes[0] / 64;
    const int E = in_sizes[1] / 2;
    const int* src = ei;
    const int* dst = ei + E;
    const int NB = (n + 255) >> BSH;
    const int nchunk = (E + CHUNK - 1) / CHUNK;
    const int nbNode = (n + 63) / 64;

    float* ws = (float*)d_ws;
    size_t off = 0;
    __half* h16  = (__half*)(ws + off); off += (size_t)n * 32;   // n*64 halves
    float* a_src = ws + off; off += (size_t)n * 4;
    float* a_dst = ws + off; off += (size_t)n * 4;
    int4* recs   = (int4*)(ws + off); off += (size_t)E * 4;
    int4* recs2  = (int4*)(ws + off); off += (size_t)E * 4;
    unsigned char* dl8 = (unsigned char*)(ws + off); off += ((size_t)E + 3) / 4;
    int* ibase  = (int*)(ws + off);
    int* gbcnt  = ibase;                       // NBMAX*PAD
    int* bcur   = ibase + NBMAX * PAD;         // NBMAX*PAD
    int* bstart = ibase + 2 * NBMAX * PAD;     // NBMAX
    int* bcount = bstart + NBMAX;              // NBMAX
    int* nstart = bcount + NBMAX;              // n
    int* ndeg   = nstart + n;                  // n

    hipMemsetAsync(gbcnt, 0, (size_t)NBMAX * PAD * sizeof(int), stream);

    k_node_hist<<<nbNode + nchunk, 256, 0, stream>>>(
        x, Wn, asrcW, adstW, h16, a_src, a_dst, n, dst, gbcnt, E, nbNode);
    k_bscan<<<1, 64, 0, stream>>>(gbcnt, bstart, bcount, bcur);
    k_pass1<<<nchunk, 512, 0, stream>>>(src, dst, ea, We, a_src, a_dst,
                                        bcur, recs, dl8, E);
    k_bin<<<NB, 1024, 0, stream>>>(bstart, bcount, recs, dl8, recs2,
                                   nstart, ndeg, n);
    k_agg<<<((size_t)n * 64 + 255) / 256, 256, 0, stream>>>(
        nstart, ndeg, recs2, h16, gamma, beta, out, n);
}

// Round 15
// 184.754 us; speedup vs baseline: 1.2532x; 1.0498x over previous
//
#include <hip/hip_runtime.h>
#include <hip/hip_fp16.h>
#include <math.h>

#define NEG_SLOPE 0.2f
#define EPS_SM 1e-8f
#define EPS_LN 1e-5f
#define PAD 16          // one global counter per 64B line
#define BSH 8           // bucket = dst >> 8  (256 nodes/bucket)
#define NBMAX 512       // max buckets (n <= 131072)
#define CHUNK 2048      // edges per bhist block
#define CHUNK1 1024     // edges per pass1 block (512 thr x 2 edges)

// round-to-nearest bf16 pair pack: returns (bf16(b)<<16) | bf16(a)
__device__ inline unsigned bf16pair(float a, float b)
{
    unsigned ua = __float_as_uint(a), ub = __float_as_uint(b);
    ua = (ua + 0x7fffu + ((ua >> 16) & 1u)) >> 16;
    ub = (ub + 0x7fffu + ((ub >> 16) & 1u)) >> 16;
    return ua | (ub << 16);
}

// ---------------------------------------------------------------------------
// Kernel 1 (fused): blocks [0, nbNode) do h = x @ W_node + a_src/a_dst
// projections (64 rows/block, register-tiled 4x4, h stored f16).
// Blocks [nbNode, nbNode+nchunk) do the bucket histogram over dst.
// ---------------------------------------------------------------------------
__global__ __launch_bounds__(256) void k_node_hist(
    const float* __restrict__ x, const float* __restrict__ Wn,
    const float* __restrict__ attn_src, const float* __restrict__ attn_dst,
    __half* __restrict__ h16, float* __restrict__ a_src, float* __restrict__ a_dst,
    int n, const int* __restrict__ dst, int* __restrict__ gbcnt, int E, int nbNode)
{
    __shared__ float Ws[64][64];   // W[k][col]   (bhist: reused as cnt[])
    __shared__ float xs[64][64];   // x[r][k]
    const int tid = threadIdx.x;

    if (blockIdx.x >= nbNode) {
        // ---- bucket histogram branch ----
        int* cnt = (int*)Ws;
        for (int i = tid; i < NBMAX; i += 256) cnt[i] = 0;
        __syncthreads();
        const int e0 = (blockIdx.x - nbNode) * CHUNK;
        const int ce = min(CHUNK, E - e0);
        for (int j = tid; j < ce; j += 256)
            atomicAdd(&cnt[((unsigned)dst[e0 + j]) >> BSH], 1);
        __syncthreads();
        for (int b = tid; b < NBMAX; b += 256)
            if (cnt[b] > 0) atomicAdd(&gbcnt[b * PAD], cnt[b]);
        return;
    }

    // ---- node GEMM branch ----
    const int row0 = blockIdx.x * 64;

    const float4* Wn4 = (const float4*)Wn;
    #pragma unroll
    for (int i = tid; i < 1024; i += 256) {
        float4 v = Wn4[i];
        *(float4*)&Ws[i >> 4][(i & 15) * 4] = v;
    }
    const float4* x4 = (const float4*)x;
    #pragma unroll
    for (int i = tid; i < 1024; i += 256) {
        int r  = i >> 4;
        int gr = row0 + r;
        float4 v = (gr < n) ? x4[(size_t)gr * 16 + (i & 15)]
                            : make_float4(0.f, 0.f, 0.f, 0.f);
        *(float4*)&xs[r][(i & 15) * 4] = v;
    }
    __syncthreads();

    const int c4 = tid & 15;
    const int r4 = tid >> 4;

    float4 acc0 = make_float4(0.f, 0.f, 0.f, 0.f);
    float4 acc1 = make_float4(0.f, 0.f, 0.f, 0.f);
    float4 acc2 = make_float4(0.f, 0.f, 0.f, 0.f);
    float4 acc3 = make_float4(0.f, 0.f, 0.f, 0.f);

    #pragma unroll 8
    for (int k = 0; k < 64; ++k) {
        float4 w = *(const float4*)&Ws[k][c4 * 4];
        float x0 = xs[r4     ][k];
        float x1 = xs[r4 + 16][k];
        float x2 = xs[r4 + 32][k];
        float x3 = xs[r4 + 48][k];
        acc0.x += x0 * w.x; acc0.y += x0 * w.y; acc0.z += x0 * w.z; acc0.w += x0 * w.w;
        acc1.x += x1 * w.x; acc1.y += x1 * w.y; acc1.z += x1 * w.z; acc1.w += x1 * w.w;
        acc2.x += x2 * w.x; acc2.y += x2 * w.y; acc2.z += x2 * w.z; acc2.w += x2 * w.w;
        acc3.x += x3 * w.x; acc3.y += x3 * w.y; acc3.z += x3 * w.z; acc3.w += x3 * w.w;
    }

    const float4 asw = *(const float4*)&attn_src[c4 * 4];
    const float4 adw = *(const float4*)&attn_dst[c4 * 4];
    const int hh = c4 >> 2;
    const bool writer = (c4 & 3) == 0;

    float4 accs[4] = {acc0, acc1, acc2, acc3};
    #pragma unroll
    for (int j = 0; j < 4; ++j) {
        int gr = row0 + r4 + 16 * j;
        if (gr < n) {
            __half2 p0 = __floats2half2_rn(accs[j].x, accs[j].y);
            __half2 p1 = __floats2half2_rn(accs[j].z, accs[j].w);
            uint2 pk = make_uint2(*reinterpret_cast<unsigned*>(&p0),
                                  *reinterpret_cast<unsigned*>(&p1));
            *(uint2*)&h16[(size_t)gr * 64 + c4 * 4] = pk;
            float ps = accs[j].x * asw.x + accs[j].y * asw.y +
                       accs[j].z * asw.z + accs[j].w * asw.w;
            float pd = accs[j].x * adw.x + accs[j].y * adw.y +
                       accs[j].z * adw.z + accs[j].w * adw.w;
            ps += __shfl_xor(ps, 1, 64); ps += __shfl_xor(ps, 2, 64);
            pd += __shfl_xor(pd, 1, 64); pd += __shfl_xor(pd, 2, 64);
            if (writer) {
                a_src[(size_t)gr * 4 + hh] = ps;
                a_dst[(size_t)gr * 4 + hh] = pd;
            }
        } else {
            float ps = 0.f, pd = 0.f;
            ps += __shfl_xor(ps, 1, 64); ps += __shfl_xor(ps, 2, 64);
            pd += __shfl_xor(pd, 1, 64); pd += __shfl_xor(pd, 2, 64);
        }
    }
}

// ---------------------------------------------------------------------------
// Kernel 2: exclusive scan of 512 bucket counts (one wave).
// ---------------------------------------------------------------------------
__global__ void k_bscan(const int* __restrict__ gbcnt,
                        int* __restrict__ bstart, int* __restrict__ bcount,
                        int* __restrict__ bcur)
{
    int lane = threadIdx.x;   // 64 threads
    int c[8]; int s = 0;
    #pragma unroll
    for (int j = 0; j < 8; ++j) { c[j] = gbcnt[(lane * 8 + j) * PAD]; s += c[j]; }
    int incl = s;
    #pragma unroll
    for (int off = 1; off < 64; off <<= 1) {
        int u = __shfl_up(incl, off, 64);
        if (lane >= off) incl += u;
    }
    int run = incl - s;
    #pragma unroll
    for (int j = 0; j < 8; ++j) {
        int b = lane * 8 + j;
        bstart[b] = run;
        bcount[b] = c[j];
        bcur[b * PAD] = run;
        run += c[j];
    }
}

// ---------------------------------------------------------------------------
// Kernel 3: bucket-grouped scatter + FULL weight computation (f32 logits).
// 512 threads, 2 edges/thread (CHUNK1=1024): register arrays halved vs the
// 4-edge variant to get under the 64-VGPR occupancy cliff, and 2x blocks
// for cross-block latency hiding. Gathers a_src[src] AND a_dst[dst]
// (L2/L3-resident), w = exp(lrelu(a_src+esc+a_dst)) packed bf16x4.
// Record: int4 { src, bf16x2(w0,w1), bf16x2(w2,w3), dst }.
// ---------------------------------------------------------------------------
__global__ __launch_bounds__(512) void k_pass1(
    const int* __restrict__ src, const int* __restrict__ dst,
    const float* __restrict__ ea, const float* __restrict__ We,
    const float* __restrict__ a_src, const float* __restrict__ a_dst,
    int* __restrict__ bcur, int4* __restrict__ rec_out,
    unsigned char* __restrict__ dl8_out, int E)
{
    __shared__ float Wes[64];       // W_edge [16][4]
    __shared__ int cnt[NBMAX];      // 2KB
    __shared__ int gpos[NBMAX];     // 2KB
    const int tid = threadIdx.x;
    if (tid < 64) Wes[tid] = We[tid];
    if (tid < NBMAX) cnt[tid] = 0;
    __syncthreads();

    const int e0 = blockIdx.x * CHUNK1;
    int d[2], s[2], rk[2];
    #pragma unroll
    for (int j = 0; j < 2; ++j) {
        int e = e0 + j * 512 + tid;
        bool v = e < E;
        d[j] = v ? dst[e] : -1;
        s[j] = v ? src[e] : 0;
    }

    #pragma unroll
    for (int j = 0; j < 2; ++j)
        rk[j] = (d[j] >= 0) ? atomicAdd(&cnt[((unsigned)d[j]) >> BSH], 1) : 0;

    float4 as4[2], ad4[2];
    #pragma unroll
    for (int j = 0; j < 2; ++j) {
        as4[j] = (d[j] >= 0) ? *(const float4*)(a_src + (size_t)s[j] * 4)
                             : make_float4(0.f, 0.f, 0.f, 0.f);
        ad4[j] = (d[j] >= 0) ? *(const float4*)(a_dst + (size_t)d[j] * 4)
                             : make_float4(0.f, 0.f, 0.f, 0.f);
    }

    int ry[2], rz[2];
    #pragma unroll
    for (int j = 0; j < 2; ++j) {
        if (d[j] < 0) { ry[j] = 0; rz[j] = 0; continue; }
        int e = e0 + j * 512 + tid;
        const float4* ea4 = (const float4*)(ea + (size_t)e * 16);
        float4 q0 = ea4[0], q1 = ea4[1], q2 = ea4[2], q3 = ea4[3];
        float eav[16] = {q0.x, q0.y, q0.z, q0.w, q1.x, q1.y, q1.z, q1.w,
                         q2.x, q2.y, q2.z, q2.w, q3.x, q3.y, q3.z, q3.w};
        float esc[4] = {0.f, 0.f, 0.f, 0.f};
        #pragma unroll
        for (int k = 0; k < 16; ++k) {
            #pragma unroll
            for (int hh = 0; hh < 4; ++hh) esc[hh] += eav[k] * Wes[k * 4 + hh];
        }
        float a0 = as4[j].x + esc[0] + ad4[j].x;
        float a1 = as4[j].y + esc[1] + ad4[j].y;
        float a2 = as4[j].z + esc[2] + ad4[j].z;
        float a3 = as4[j].w + esc[3] + ad4[j].w;
        a0 = (a0 >= 0.f) ? a0 : NEG_SLOPE * a0;
        a1 = (a1 >= 0.f) ? a1 : NEG_SLOPE * a1;
        a2 = (a2 >= 0.f) ? a2 : NEG_SLOPE * a2;
        a3 = (a3 >= 0.f) ? a3 : NEG_SLOPE * a3;
        ry[j] = (int)bf16pair(__expf(a0), __expf(a1));
        rz[j] = (int)bf16pair(__expf(a2), __expf(a3));
    }
    __syncthreads();

    if (tid < NBMAX) {
        int c = cnt[tid];
        if (c > 0) gpos[tid] = atomicAdd(&bcur[tid * PAD], c);
    }
    __syncthreads();

    #pragma unroll
    for (int j = 0; j < 2; ++j) {
        if (d[j] < 0) continue;
        int g = gpos[((unsigned)d[j]) >> BSH] + rk[j];
        rec_out[g] = make_int4(s[j], ry[j], rz[j], d[j]);
        dl8_out[g] = (unsigned char)(d[j] & 255);
    }
}

// ---------------------------------------------------------------------------
// Kernel 4: per-bucket counting sort to per-node-contiguous order (pure
// permutation — weights already in the record). Emits recs2 + nstart/ndeg.
// ---------------------------------------------------------------------------
__global__ __launch_bounds__(1024) void k_bin(
    const int* __restrict__ bstart, const int* __restrict__ bcount,
    const int4* __restrict__ recs, const unsigned char* __restrict__ dl8,
    int4* __restrict__ recs2, int* __restrict__ nstart, int* __restrict__ ndeg,
    int n)
{
    __shared__ int cnt[256], st[256], cur[256];
    const int b    = blockIdx.x;
    const int tid  = threadIdx.x;
    const int nbase = b << BSH;
    const int base = bstart[b];
    const int bcnt = bcount[b];

    if (tid < 256) cnt[tid] = 0;
    __syncthreads();

    for (int i = tid; i < bcnt; i += 1024)
        atomicAdd(&cnt[dl8[base + i]], 1);
    __syncthreads();

    if (tid < 64) {
        int c0 = cnt[4 * tid], c1 = cnt[4 * tid + 1];
        int c2 = cnt[4 * tid + 2], c3 = cnt[4 * tid + 3];
        int s = c0 + c1 + c2 + c3;
        int incl = s;
        #pragma unroll
        for (int off = 1; off < 64; off <<= 1) {
            int u = __shfl_up(incl, off, 64);
            if (tid >= off) incl += u;
        }
        int run = incl - s;
        st[4 * tid    ] = run; cur[4 * tid    ] = run; run += c0;
        st[4 * tid + 1] = run; cur[4 * tid + 1] = run; run += c1;
        st[4 * tid + 2] = run; cur[4 * tid + 2] = run; run += c2;
        st[4 * tid + 3] = run; cur[4 * tid + 3] = run;
    }
    __syncthreads();

    if (tid < 256) {
        int node = nbase + tid;
        if (node < n) {
            nstart[node] = base + st[tid];
            ndeg[node]   = cnt[tid];
        }
    }

    for (int i = tid; i < bcnt; i += 1024) {
        int4 r = recs[base + i];
        int p = atomicAdd(&cur[r.w & 255], 1);
        recs2[base + p] = r;
    }
}

// ---------------------------------------------------------------------------
// Kernel 5: wave-per-node aggregation + residual + LayerNorm.
// Record addresses are wave-uniform (readfirstlane -> scalar cache),
// freeing the VMEM pipe for h-gathers. Per edge: select + 2 bit-ops +
// fma + add + h16 cvt.
// ---------------------------------------------------------------------------
__global__ __launch_bounds__(256) void k_agg(
    const int* __restrict__ nstart, const int* __restrict__ ndeg,
    const int4* __restrict__ recs2, const __half* __restrict__ h16,
    const float* __restrict__ gamma, const float* __restrict__ beta,
    float* __restrict__ out, int n)
{
    int gid  = blockIdx.x * 256 + threadIdx.x;
    int node = gid >> 6;
    int lane = gid & 63;
    if (node >= n) return;
    const int hh   = lane >> 4;
    const int wsh  = (hh & 1) ? 0 : 16;   // bf16 lane-slot shift

    const unsigned rs = (unsigned)__builtin_amdgcn_readfirstlane(nstart[node]);
    const int deg     = __builtin_amdgcn_readfirstlane(ndeg[node]);
    const int4* pr = recs2 + rs;

    const float h_node = __half2float(h16[((unsigned)node << 6) | lane]);

    float sum = 0.f, accv = 0.f;

#define PROC_EDGE(HV, YW, ZW)                                            \
    {                                                                    \
        int w_ = (hh < 2) ? (YW) : (ZW);                                 \
        float wf_ = __int_as_float(((unsigned)w_ << wsh) & 0xffff0000u); \
        sum  += wf_;                                                     \
        accv += wf_ * (HV);                                              \
    }

    int i = 0;
    for (; i + 8 <= deg; i += 8) {
        int4 r[8];
        #pragma unroll
        for (int j = 0; j < 8; ++j) r[j] = pr[i + j];   // wave-uniform (SMEM)
        float hv[8];
        #pragma unroll
        for (int j = 0; j < 8; ++j)
            hv[j] = __half2float(h16[((unsigned)r[j].x << 6) | lane]);
        #pragma unroll
        for (int j = 0; j < 8; ++j) PROC_EDGE(hv[j], r[j].y, r[j].z);
    }
    for (; i < deg; ++i) {
        int4 r0 = pr[i];
        float hv0 = __half2float(h16[((unsigned)r0.x << 6) | lane]);
        PROC_EDGE(hv0, r0.y, r0.z);
    }
#undef PROC_EDGE

    float y = accv / (sum + EPS_SM) + h_node;

    float t1 = y;
    #pragma unroll
    for (int off = 32; off; off >>= 1) t1 += __shfl_xor(t1, off, 64);
    float mu = t1 * (1.f / 64.f);
    float dv = y - mu;
    float vs = dv * dv;
    #pragma unroll
    for (int off = 32; off; off >>= 1) vs += __shfl_xor(vs, off, 64);
    float var = vs * (1.f / 64.f);
    out[((unsigned)node << 6) | lane] =
        dv * rsqrtf(var + EPS_LN) * gamma[lane] + beta[lane];
}

// ---------------------------------------------------------------------------
extern "C" void kernel_launch(void* const* d_in, const int* in_sizes, int n_in,
                              void* d_out, int out_size, void* d_ws, size_t ws_size,
                              hipStream_t stream)
{
    const float* x     = (const float*)d_in[0];
    const int*   ei    = (const int*)  d_in[1];
    const float* ea    = (const float*)d_in[2];
    const float* Wn    = (const float*)d_in[3];
    const float* We    = (const float*)d_in[4];
    const float* asrcW = (const float*)d_in[5];
    const float* adstW = (const float*)d_in[6];
    const float* gamma = (const float*)d_in[7];
    const float* beta  = (const float*)d_in[8];
    float* out = (float*)d_out;

    const int n = in_sizes[0] / 64;
    const int E = in_sizes[1] / 2;
    const int* src = ei;
    const int* dst = ei + E;
    const int NB = (n + 255) >> BSH;
    const int nchunk  = (E + CHUNK  - 1) / CHUNK;
    const int nchunk1 = (E + CHUNK1 - 1) / CHUNK1;
    const int nbNode = (n + 63) / 64;

    float* ws = (float*)d_ws;
    size_t off = 0;
    __half* h16  = (__half*)(ws + off); off += (size_t)n * 32;   // n*64 halves
    float* a_src = ws + off; off += (size_t)n * 4;
    float* a_dst = ws + off; off += (size_t)n * 4;
    int4* recs   = (int4*)(ws + off); off += (size_t)E * 4;
    int4* recs2  = (int4*)(ws + off); off += (size_t)E * 4;
    unsigned char* dl8 = (unsigned char*)(ws + off); off += ((size_t)E + 3) / 4;
    int* ibase  = (int*)(ws + off);
    int* gbcnt  = ibase;                       // NBMAX*PAD
    int* bcur   = ibase + NBMAX * PAD;         // NBMAX*PAD
    int* bstart = ibase + 2 * NBMAX * PAD;     // NBMAX
    int* bcount = bstart + NBMAX;              // NBMAX
    int* nstart = bcount + NBMAX;              // n
    int* ndeg   = nstart + n;                  // n

    hipMemsetAsync(gbcnt, 0, (size_t)NBMAX * PAD * sizeof(int), stream);

    k_node_hist<<<nbNode + nchunk, 256, 0, stream>>>(
        x, Wn, asrcW, adstW, h16, a_src, a_dst, n, dst, gbcnt, E, nbNode);
    k_bscan<<<1, 64, 0, stream>>>(gbcnt, bstart, bcount, bcur);
    k_pass1<<<nchunk1, 512, 0, stream>>>(src, dst, ea, We, a_src, a_dst,
                                         bcur, recs, dl8, E);
    k_bin<<<NB, 1024, 0, stream>>>(bstart, bcount, recs, dl8, recs2,
                                   nstart, ndeg, n);
    k_agg<<<((size_t)n * 64 + 255) / 256, 256, 0, stream>>>(
        nstart, ndeg, recs2, h16, gamma, beta, out, n);
}